// Round 7
// baseline (329.888 us; speedup 1.0000x reference)
//
#include <hip/hip_runtime.h>
#include <stdint.h>

#define Bb 64
#define Hh 128
#define Ww 128
#define Cc 21
#define Pp 49152          // NUM_SAMPLED
#define Kk 36864          // NUM_UNCERTAIN
#define NR 12288          // NUM_RANDOM

// digit split over key bits [16,47): 10 + 10 + 11  (bits >= 47 are zero)
#define SH0 16
#define SH1 26
#define SH2 36
#define NB01 1024
#define NB2  2048

#define TILE 2048         // elements per sort tile
#define TILES 24          // Pp / TILE
#define NBLK (Bb * TILES) // 1536 sample/hist/scatter blocks
#define ITER (TILE / 256) // 8 elements per thread
#define HWORDS01 ((size_t)Bb * NB01 * TILES)  // u32 words, 1024-bin table (6.29 MB)

typedef uint32_t u32;
typedef uint64_t u64;
typedef unsigned short u16;

// XCD-affine decode: all TILES blocks of segment s have blk%8 == s%8, so the
// round-robin block->XCD dispatch keeps a segment's r/w window in ONE XCD's
// L2. Performance heuristic only; correctness never depends on placement.
#define DECODE_ST const int s = blk & 63; const int t = blk >> 6;

// NBITS-wide ballot digit-match: mask of lanes in this wave holding digit d.
template<int NBITS>
__device__ __forceinline__ u64 matchN(u32 d) {
    u64 m = ~0ull;
    #pragma unroll
    for (int bit = 0; bit < NBITS; ++bit) {
        u64 bl = __ballot((d >> bit) & 1u);
        m &= ((d >> bit) & 1u) ? bl : ~bl;
    }
    return m;
}

// ---------------------------------------------------------------------------
// Kernel 0: compact channel-0 plane: planes[b][h][w] = logits[b][h][w][0].
// ---------------------------------------------------------------------------
__global__ __launch_bounds__(256) void extract_kernel(const float* __restrict__ logits,
                                                      float* __restrict__ planes) {
    int gid = blockIdx.x * blockDim.x + threadIdx.x;   // [0, B*H*W)
    planes[gid] = logits[(size_t)gid * Cc];
}

// ---------------------------------------------------------------------------
// Kernel 1: bilinear sample (64 KB plane staged in LDS), build sortable key,
// fused pass-0 per-tile histogram. key = fp32 bits of |interp| (order-
// isomorphic for non-negative floats); element = (key << 16) | idx.
// fp contract OFF: the sort permutation feeds the output directly — bit-exact
// numpy arithmetic required (one rank flip = O(1) absmax error).
// ---------------------------------------------------------------------------
__global__ __launch_bounds__(256) void sample_key_kernel(const float* __restrict__ planes,
                                                         const float2* __restrict__ coords,
                                                         u64* __restrict__ keys,
                                                         u32* __restrict__ hist) {
#pragma clang fp contract(off)
    __shared__ float pl[Hh * Ww];      // 64 KB
    __shared__ u32 h[NB01];            // 4 KB
    const int tid = threadIdx.x;
    const int blk = blockIdx.x;
    DECODE_ST

    for (int i = tid; i < NB01; i += 256) h[i] = 0;
    const float4* p4 = (const float4*)(planes + s * (Hh * Ww));
    float4* l4 = (float4*)pl;
    #pragma unroll
    for (int i = 0; i < 16; ++i) l4[i * 256 + tid] = p4[i * 256 + tid];
    __syncthreads();

    #pragma unroll 4
    for (int i = 0; i < ITER; ++i) {
        int idx = t * TILE + i * 256 + tid;            // point index within segment
        int gid = s * Pp + idx;
        float2 c = coords[gid];
        float xf = c.x * 127.0f;                       // coords[...,0] -> H axis
        float yf = c.y * 127.0f;                       // coords[...,1] -> W axis
        float x0 = floorf(xf), x1 = ceilf(xf);
        float y0 = floorf(yf), y1 = ceilf(yf);
        float mux = xf - x0;
        float muy = yf - y0;
        int x0i = (int)x0, x1i = (int)x1, y0i = (int)y0, y1i = (int)y1;
        float p1 = pl[x0i * Ww + y0i];
        float p2 = pl[x1i * Ww + y0i];
        float p3 = pl[x0i * Ww + y1i];
        float p4v = pl[x1i * Ww + y1i];
        float p12 = p1 * (1.0f - mux) + p2 * mux;
        float p34 = p3 * (1.0f - mux) + p4v * mux;
        float r   = p12 * (1.0f - muy) + p34 * muy;
        u32 kb = __float_as_uint(r) & 0x7fffffffu;     // |r| bits
        keys[gid] = ((u64)kb << 16) | (u32)idx;
        atomicAdd(&h[kb & (NB01 - 1)], 1u);            // pass-0 digit (uniform)
    }
    __syncthreads();
    for (int j = 0; j < NB01 / 256; ++j) {
        int d = tid * (NB01 / 256) + j;
        hist[((size_t)s * NB01 + d) * TILES + t] = h[d];
    }
}

// ---------------------------------------------------------------------------
// Kernel 2 (passes 1,2): per-tile histogram via per-wave privatized LDS
// counters + plain atomicAdd (round-6 lesson: far cheaper than ballots).
// ---------------------------------------------------------------------------
template<int NB, int SHIFT>
__global__ __launch_bounds__(256) void hist_kernel(const u64* __restrict__ in,
                                                   u32* __restrict__ hist) {
    __shared__ u32 h[4][NB];
    const int tid = threadIdx.x;
    const int w = tid >> 6;
    const int blk = blockIdx.x;
    DECODE_ST
    for (int i = tid; i < 4 * NB; i += 256) ((u32*)h)[i] = 0;
    __syncthreads();
    const u64* src = in + (size_t)s * Pp + t * TILE;
    #pragma unroll 4
    for (int i = 0; i < ITER; ++i) {
        u64 v = src[i * 256 + tid];
        u32 d = (u32)(v >> SHIFT) & (NB - 1);
        atomicAdd(&h[w][d], 1u);
    }
    __syncthreads();
    for (int j = 0; j < NB / 256; ++j) {
        int d = tid * (NB / 256) + j;
        hist[((size_t)s * NB + d) * TILES + t] = h[0][d] + h[1][d] + h[2][d] + h[3][d];
    }
}

// ---------------------------------------------------------------------------
// Kernel 3: per-segment exclusive scan: dst[s][d][t] = prefix of src counts
// in (digit, tile) order. src may equal dst (in-place).
// ---------------------------------------------------------------------------
template<int NB>
__global__ __launch_bounds__(1024) void scan_kernel(const u32* __restrict__ src,
                                                    u32* __restrict__ dst) {
    constexpr int DPT = NB / 1024;
    __shared__ u32 wsum[16];
    const int s = blockIdx.x;
    const int tid = threadIdx.x;
    const int lane = tid & 63;
    const int w = tid >> 6;
    const u32* sb = src + (size_t)s * NB * TILES;
    u32* db = dst + (size_t)s * NB * TILES;

    u32 c[DPT][TILES];
    u32 dt[DPT];
    u32 ts = 0;
    #pragma unroll
    for (int j = 0; j < DPT; ++j) {
        int d = tid * DPT + j;
        u32 acc = 0;
        #pragma unroll
        for (int t = 0; t < TILES; ++t) { c[j][t] = sb[d * TILES + t]; acc += c[j][t]; }
        dt[j] = acc;
        ts += acc;
    }

    u32 sc = ts;
    for (int o = 1; o < 64; o <<= 1) {
        u32 n = __shfl_up(sc, o);
        if (lane >= o) sc += n;
    }
    if (lane == 63) wsum[w] = sc;
    __syncthreads();
    if (tid == 0) {
        u32 run = 0;
        for (int i = 0; i < 16; ++i) { u32 v = wsum[i]; wsum[i] = run; run += v; }
    }
    __syncthreads();
    u32 r = sc - ts + wsum[w];
    #pragma unroll
    for (int j = 0; j < DPT; ++j) {
        int d = tid * DPT + j;
        #pragma unroll
        for (int t = 0; t < TILES; ++t) { db[d * TILES + t] = r; r += c[j][t]; }
    }
}

// ---------------------------------------------------------------------------
// Kernel 4: stable scatter with LDS local reorder + linear run-contiguous
// global write. matchN computed ONCE per element (cached digit/rank/count/
// leader flags reused in phase B). No global-atomic hist fusion (round-5
// lesson). FINAL==1: emit out[s][g] = coords[s][idx] directly for g < K.
// ---------------------------------------------------------------------------
template<int NB, int NBITS, int FINAL>
__global__ __launch_bounds__(256) void scatter_kernel(const u64* __restrict__ in,
                                                      u64* __restrict__ out_keys,
                                                      const u32* __restrict__ off,
                                                      int shift,
                                                      const float2* __restrict__ coords,
                                                      float2* __restrict__ out) {
    __shared__ u64 el[TILE];           // 16 KB
    __shared__ u16 wh[NB * 4];         // 8/16 KB  [digit][wave] counts -> local bases
    __shared__ u16 dl[NB];             // 2/4 KB   delta[d] (mod 2^16)
    __shared__ u32 aux[4];
    const int tid = threadIdx.x;
    const int lane = tid & 63;
    const int w = tid >> 6;
    const int blk = blockIdx.x;
    DECODE_ST
    const u64* src = in + (size_t)s * Pp + t * TILE;

    for (int i = tid; i < NB * 4; i += 256) wh[i] = 0;
    u64 v[ITER];
    #pragma unroll
    for (int i = 0; i < ITER; ++i) v[i] = src[w * (TILE / 4) + i * 64 + lane];
    __syncthreads();

    // phase A: per-wave digit histogram; cache match results for phase B.
    // pk[i] = before | (cnt << 8) | (leader << 16)
    const u64 ltmask = (1ull << lane) - 1ull;
    u32 dg[ITER], pk[ITER];
    volatile u16* vwh = wh;
    #pragma unroll 2
    for (int i = 0; i < ITER; ++i) {
        u32 d = (u32)(v[i] >> shift) & (NB - 1);
        u64 m = matchN<NBITS>(d);
        u32 before = (u32)__popcll(m & ltmask);
        u32 cnt = (u32)__popcll(m);
        bool lead = (lane == __ffsll((unsigned long long)m) - 1);
        dg[i] = d;
        pk[i] = before | (cnt << 8) | (lead ? 0x10000u : 0u);
        if (lead) {
            u32 p = d * 4 + w;
            vwh[p] = (u16)(vwh[p] + cnt);
        }
    }
    __syncthreads();

    // scan: thread owns NB/256 digits; local digit bases + per-wave bases.
    constexpr int DPT = NB / 256;
    const int d0 = tid * DPT;
    u32 dtot[DPT];
    u32 t8 = 0;
    #pragma unroll
    for (int j = 0; j < DPT; ++j) {
        int d = d0 + j;
        u32 c = (u32)wh[d * 4 + 0] + wh[d * 4 + 1] + wh[d * 4 + 2] + wh[d * 4 + 3];
        dtot[j] = c;
        t8 += c;
    }
    u32 sc = t8;
    for (int o = 1; o < 64; o <<= 1) {
        u32 n = __shfl_up(sc, o);
        if (lane >= o) sc += n;
    }
    if (lane == 63) aux[w] = sc;
    __syncthreads();
    if (tid == 0) {
        u32 run = 0;
        for (int i = 0; i < 4; ++i) { u32 x = aux[i]; aux[i] = run; run += x; }
    }
    __syncthreads();
    u32 run = sc - t8 + aux[w];       // exclusive base for this thread's digits
    #pragma unroll
    for (int j = 0; j < DPT; ++j) {
        int d = d0 + j;
        u32 ls = run;                 // local_start[d]
        u32 g = off[((size_t)s * NB + d) * TILES + t];
        dl[d] = (u16)(g - ls);
        u32 c0 = wh[d * 4 + 0], c1 = wh[d * 4 + 1], c2 = wh[d * 4 + 2];
        wh[d * 4 + 0] = (u16)ls;
        wh[d * 4 + 1] = (u16)(ls + c0);
        wh[d * 4 + 2] = (u16)(ls + c0 + c1);
        wh[d * 4 + 3] = (u16)(ls + c0 + c1 + c2);
        run += dtot[j];
    }
    __syncthreads();

    // phase B: stable scatter into LDS using cached ranks (no ballots here).
    #pragma unroll 2
    for (int i = 0; i < ITER; ++i) {
        u32 d = dg[i];
        u32 before = pk[i] & 0xffu;
        u32 base = vwh[d * 4 + w];
        el[base + before] = v[i];
        if (pk[i] & 0x10000u)
            vwh[d * 4 + w] = (u16)(base + ((pk[i] >> 8) & 0xffu));
    }
    __syncthreads();

    // phase C: linear read-back, run-contiguous global write.
    if (!FINAL) {
        u64* dst = out_keys + (size_t)s * Pp;
        #pragma unroll 2
        for (int i = 0; i < ITER; ++i) {
            int pos = i * 256 + tid;
            u64 e = el[pos];
            u32 d = (u32)(e >> shift) & (NB - 1);
            u32 g = (u32)(u16)(pos + dl[d]);
            dst[g] = e;
        }
    } else {
        const float2* cseg = coords + (size_t)s * Pp;
        float2* oseg = out + (size_t)s * Pp;
        #pragma unroll 2
        for (int i = 0; i < ITER; ++i) {
            int pos = i * 256 + tid;
            u64 e = el[pos];
            u32 d = (u32)(e >> shift) & (NB - 1);
            u32 g = (u32)(u16)(pos + dl[d]);
            if (g < Kk) {
                u32 idx = (u32)e & 0xffffu;
                oseg[g] = cseg[idx];
            }
        }
    }
}

// ---------------------------------------------------------------------------
// Kernel 5: copy extra_random into rows [K, P) of each segment.
// ---------------------------------------------------------------------------
__global__ __launch_bounds__(256) void extra_copy_kernel(const float2* __restrict__ extra,
                                                         float2* __restrict__ out) {
    int gid = blockIdx.x * blockDim.x + threadIdx.x;   // [0, B*NR)
    int b = gid / NR;
    int j = gid - b * NR;
    out[(size_t)b * Pp + Kk + j] = extra[gid];
}

extern "C" void kernel_launch(void* const* d_in, const int* in_sizes, int n_in,
                              void* d_out, int out_size, void* d_ws, size_t ws_size,
                              hipStream_t stream) {
    const float*  logits = (const float*)d_in[0];   // (B,H,W,C) fp32
    const float2* coords = (const float2*)d_in[1];  // (B,P,2)  fp32
    const float2* extra  = (const float2*)d_in[2];  // (B,NR,2) fp32
    float2* out = (float2*)d_out;

    u64* buf0 = (u64*)d_ws;                          // 25.2 MB
    u64* buf1 = buf0 + (size_t)Bb * Pp;              // 25.2 MB (ping-pong)
    float* planes = (float*)buf1;                    // 4 MB; dead before pass-0 scatter writes buf1
    u32* histA = (u32*)d_out;                        // 6.3 MB scratch (passes 0,1); d_out untouched until final pass
    u32* histC = (u32*)buf1;                         // pass-2 table (12.6 MB) in buf1 (dead after pass 1;
                                                     // final scatter overwrites all of d_out, so offsets live here)

    // All launches are on one stream -> sequential; buffer reuse is hazard-free.
    extract_kernel<<<(Bb * Hh * Ww) / 256, 256, 0, stream>>>(logits, planes);
    sample_key_kernel<<<NBLK, 256, 0, stream>>>(planes, coords, buf0, histA);

    // pass 0: bits [16,26)  buf0 -> buf1
    scan_kernel<NB01><<<Bb, 1024, 0, stream>>>(histA, histA);
    scatter_kernel<NB01, 10, 0><<<NBLK, 256, 0, stream>>>(buf0, buf1, histA, SH0, nullptr, nullptr);
    // pass 1: bits [26,36)  buf1 -> buf0
    hist_kernel<NB01, SH1><<<NBLK, 256, 0, stream>>>(buf1, histA);
    scan_kernel<NB01><<<Bb, 1024, 0, stream>>>(histA, histA);
    scatter_kernel<NB01, 10, 0><<<NBLK, 256, 0, stream>>>(buf1, buf0, histA, SH1, nullptr, nullptr);
    // pass 2: bits [36,47)  buf0 -> out (fused gather+emit)
    hist_kernel<NB2, SH2><<<NBLK, 256, 0, stream>>>(buf0, histC);
    scan_kernel<NB2><<<Bb, 1024, 0, stream>>>(histC, histC);
    scatter_kernel<NB2, 11, 1><<<NBLK, 256, 0, stream>>>(buf0, nullptr, histC, SH2, coords, out);

    extra_copy_kernel<<<(Bb * NR) / 256, 256, 0, stream>>>(extra, out);
}